// Round 11
// baseline (98.840 us; speedup 1.0000x reference)
//
#include <hip/hip_runtime.h>
#include <hip/hip_bf16.h>
#include <math.h>

// Problem constants: [N, L, H, D] = [4, 8192, 8, 64], Dv = 64, fp32 in/out.
#define N_    4
#define L_    8192
#define H_    8
#define NH_   32           // N*H
#define CHK   64           // chunk length
#define NC_   128          // chunks per (n,h)
#define ROWF  512          // H_*D_ floats between consecutive l
#define EPSF  1e-6f

typedef __attribute__((ext_vector_type(8))) short bf16x8;   // 8 bf16 = 4 VGPRs
typedef __attribute__((ext_vector_type(4))) float f32x4;
typedef __attribute__((ext_vector_type(4))) unsigned short us4;

__device__ __forceinline__ float fmap(float x) { return x > 0.f ? x + 1.f : __expf(x); }

// native conversion: compiler fuses adjacent pairs into v_cvt_pk_bf16_f32
__device__ __forceinline__ unsigned short c2bf(float x) {
  __hip_bfloat16 b = __float2bfloat16(x);
  return *reinterpret_cast<unsigned short*>(&b);
}
__device__ __forceinline__ float bf2f(unsigned short u) {
  return __uint_as_float(((unsigned)u) << 16);
}

// Swizzled ushort index into a row-major [64] bf16 LDS tile (row stride 128 B).
__device__ __forceinline__ int sidx(int row, int col) {
  return row * 64 + (col ^ ((row & 7) << 3));
}

__device__ __forceinline__ f32x4 MFMA(bf16x8 a, bf16x8 b, f32x4 c) {
  return __builtin_amdgcn_mfma_f32_16x16x32_bf16(a, b, c, 0, 0, 0);
}

// ---------------- Pass A: per-chunk totals T_c (direct frag stores) + K colsums ----------------
__global__ __launch_bounds__(256) void k_chunk_tot(const float* __restrict__ keys,
                                                   const float* __restrict__ values,
                                                   unsigned short* __restrict__ Tws,
                                                   float* __restrict__ Kcs) {
  __shared__ __align__(16) unsigned short Kt[64 * 64];  // K^T [d][s] (fmap, bf16)
  __shared__ __align__(16) unsigned short Vt[64 * 64];  // V^T [e][s]
  __shared__ float kacc[64];
  const int bid = blockIdx.x;             // nh*NC_ + c
  const int nh = bid / NC_, c = bid % NC_;
  const int n = nh / H_, h = nh % H_;
  const int tid = threadIdx.x;
  const int lane = tid & 63;
  const int wv = tid >> 6;
  const int lane15 = lane & 15, lg = lane >> 4;
  const int arow = wv * 16 + lane15;      // e-row for the V fragment

  if (tid < 64) kacc[tid] = 0.f;

  // transposed staging: thread owns column d, 16 rows (coalesced across lanes)
  const int d = tid & 63, sg = tid >> 6;
  const size_t gbase = ((size_t)(n * L_ + c * CHK)) * ROWF + h * 64 + d;
  float kr[16], vr[16];
#pragma unroll
  for (int i = 0; i < 16; ++i) kr[i] = keys[gbase + (size_t)(sg * 16 + i) * ROWF];
#pragma unroll
  for (int i = 0; i < 16; ++i) vr[i] = values[gbase + (size_t)(sg * 16 + i) * ROWF];

  float kpart = 0.f;
#pragma unroll
  for (int i = 0; i < 16; ++i) { kr[i] = fmap(kr[i]); kpart += kr[i]; }
#pragma unroll
  for (int i = 0; i < 16; i += 4) {
    us4 wk, wvv;
#pragma unroll
    for (int j = 0; j < 4; ++j) { wk[j] = c2bf(kr[i + j]); wvv[j] = c2bf(vr[i + j]); }
    *(us4*)&Kt[sidx(d, sg * 16 + i)] = wk;
    *(us4*)&Vt[sidx(d, sg * 16 + i)] = wvv;
  }
  atomicAdd(&kacc[d], kpart);   // LDS atomics drain before the barrier
  __syncthreads();              // B1: tiles + kacc complete

  // swapped MFMA: lane holds T[e = arow][d = nt*16 + lg*4 + r]
  const bf16x8 av0 = *(const bf16x8*)&Vt[sidx(arow, lg * 8)];
  const bf16x8 av1 = *(const bf16x8*)&Vt[sidx(arow, (lg + 4) * 8)];
  unsigned short* Tp = Tws + (size_t)bid * 4096;
#pragma unroll
  for (int nt = 0; nt < 4; ++nt) {
    const int brow = nt * 16 + lane15;   // d-window
    f32x4 acc = {0.f, 0.f, 0.f, 0.f};
    acc = MFMA(*(const bf16x8*)&Kt[sidx(brow, lg * 8)], av0, acc);
    acc = MFMA(*(const bf16x8*)&Kt[sidx(brow, (lg + 4) * 8)], av1, acc);
    us4 w;
#pragma unroll
    for (int r = 0; r < 4; ++r) w[r] = c2bf(acc[r]);
    // direct store, plain row-major e*64+d (fragment-native, 8B contiguous)
    *(us4*)&Tp[arow * 64 + nt * 16 + lg * 4] = w;
  }
  if (tid < 64) Kcs[(size_t)bid * 64 + tid] = kacc[tid];
}

// ---------------- Pass B: in-place exclusive prefix over chunks (depth 32, 4-wide) ----------------
// Elementwise at fixed flat index -> layout-agnostic.
__global__ __launch_bounds__(256) void k_scan(unsigned short* __restrict__ Tws,
                                              float* __restrict__ Kcs) {
  const int tid = threadIdx.x;
  if (blockIdx.x < 512) {
    const int gid = blockIdx.x * 256 + tid;          // 0 .. 131071
    const int nh = gid >> 12, de = gid & 4095;
    unsigned short* p = Tws + (size_t)nh * NC_ * 4096 + de;
    float run = 0.f;
    for (int s = 0; s < 32; ++s) {
      const float x0 = bf2f(p[(size_t)(s * 4 + 0) * 4096]);
      const float x1 = bf2f(p[(size_t)(s * 4 + 1) * 4096]);
      const float x2 = bf2f(p[(size_t)(s * 4 + 2) * 4096]);
      const float x3 = bf2f(p[(size_t)(s * 4 + 3) * 4096]);
      p[(size_t)(s * 4 + 0) * 4096] = c2bf(run);
      p[(size_t)(s * 4 + 1) * 4096] = c2bf(run + x0);
      p[(size_t)(s * 4 + 2) * 4096] = c2bf(run + x0 + x1);
      p[(size_t)(s * 4 + 3) * 4096] = c2bf(run + x0 + x1 + x2);
      run += x0 + x1 + x2 + x3;
    }
  } else {
    const int gid = (blockIdx.x - 512) * 256 + tid;  // 0 .. 2047
    const int nh = gid >> 6, d = gid & 63;
    float* p = Kcs + (size_t)nh * NC_ * 64 + d;
    float run = 0.f;
    for (int s = 0; s < 32; ++s) {
      const float x0 = p[(size_t)(s * 4 + 0) * 64];
      const float x1 = p[(size_t)(s * 4 + 1) * 64];
      const float x2 = p[(size_t)(s * 4 + 2) * 64];
      const float x3 = p[(size_t)(s * 4 + 3) * 64];
      p[(size_t)(s * 4 + 0) * 64] = run;
      p[(size_t)(s * 4 + 1) * 64] = run + x0;
      p[(size_t)(s * 4 + 2) * 64] = run + x0 + x1;
      p[(size_t)(s * 4 + 3) * 64] = run + x0 + x1 + x2;
      run += x0 + x1 + x2 + x3;
    }
  }
}

// ---------------- Pass C: per-chunk output; St/kpre direct from global ----------------
__global__ __launch_bounds__(256) void k_output(const float* __restrict__ queries,
                                                const float* __restrict__ keys,
                                                const float* __restrict__ values,
                                                const unsigned short* __restrict__ Pws,
                                                const float* __restrict__ Kpre,
                                                float* __restrict__ out) {
  __shared__ __align__(16) unsigned short Ks[64 * 64];  // K rows (fmap); after B2: attn rows
  __shared__ __align__(16) unsigned short Vt[64 * 64];  // V^T [e][s]

  // XCD-aware swizzle: 4096 % 8 == 0 -> bijective
  const int wg = blockIdx.x;
  const int bid = (wg & 7) * (NH_ * NC_ / 8) + (wg >> 3);
  const int nh = bid / NC_, c = bid % NC_;
  const int n = nh / H_, h = nh % H_;
  const int tid = threadIdx.x;
  const int lane = tid & 63;
  const int wv = tid >> 6;
  const int lane15 = lane & 15, lg = lane >> 4;
  const int t0w = wv * 16;
  const int trow = t0w + lane15;          // this lane's attn/output row (wave-local)
  const int l0 = c * CHK;
  const size_t tb = (size_t)bid * 4096;
  const size_t kb = (size_t)bid * 64;

  // ---- issue all global loads ----
  // K rows (coalesced float4)
  const int r0 = tid >> 4, c4 = (tid & 15) * 4;
  float4 krow[4];
#pragma unroll
  for (int rep = 0; rep < 4; ++rep)
    krow[rep] = *(const float4*)&keys[((size_t)(n * L_ + l0 + r0 + rep * 16)) * ROWF + h * 64 + c4];
  // Q (row trow)
  const size_t qg = ((size_t)(n * L_ + l0 + trow)) * ROWF + h * 64;
  const float4 q0 = *(const float4*)&queries[qg + lg * 8];
  const float4 q1 = *(const float4*)&queries[qg + lg * 8 + 4];
  const float4 q2 = *(const float4*)&queries[qg + 32 + lg * 8];
  const float4 q3 = *(const float4*)&queries[qg + 32 + lg * 8 + 4];
  // V^T (transposed scalar, coalesced across lanes)
  const int d = tid & 63, sg = tid >> 6;
  const size_t vbase = ((size_t)(n * L_ + l0)) * ROWF + h * 64 + d;
  float vr[16];
#pragma unroll
  for (int i = 0; i < 16; ++i) vr[i] = values[vbase + (size_t)(sg * 16 + i) * ROWF];
  // St B-fragments direct from ws (plain e*64+d layout; L2-hot)
  bf16x8 stf0[4], stf1[4];
#pragma unroll
  for (int nt = 0; nt < 4; ++nt) {
    const int brow = nt * 16 + lane15;
    stf0[nt] = *(const bf16x8*)&Pws[tb + brow * 64 + lg * 8];
    stf1[nt] = *(const bf16x8*)&Pws[tb + brow * 64 + 32 + lg * 8];
  }
  // kpre slices for the zden dot (broadcast within 16-lane groups; L2-hot)
  const float4 kp0 = *(const float4*)&Kpre[kb + lg * 8];
  const float4 kp1 = *(const float4*)&Kpre[kb + lg * 8 + 4];
  const float4 kp2 = *(const float4*)&Kpre[kb + 32 + lg * 8];
  const float4 kp3 = *(const float4*)&Kpre[kb + 32 + lg * 8 + 4];

  // ---- convert + LDS writes ----
#pragma unroll
  for (int rep = 0; rep < 4; ++rep) {
    us4 uk;
    uk[0] = c2bf(fmap(krow[rep].x)); uk[1] = c2bf(fmap(krow[rep].y));
    uk[2] = c2bf(fmap(krow[rep].z)); uk[3] = c2bf(fmap(krow[rep].w));
    *(us4*)&Ks[sidx(r0 + rep * 16, c4)] = uk;
  }
#pragma unroll
  for (int i = 0; i < 16; i += 4) {
    us4 w;
#pragma unroll
    for (int j = 0; j < 4; ++j) w[j] = c2bf(vr[i + j]);
    *(us4*)&Vt[sidx(d, sg * 16 + i)] = w;
  }
  // Q: fmap in fp32 (also feeds the zden dot), then convert
  const float4 f0 = make_float4(fmap(q0.x), fmap(q0.y), fmap(q0.z), fmap(q0.w));
  const float4 f1 = make_float4(fmap(q1.x), fmap(q1.y), fmap(q1.z), fmap(q1.w));
  const float4 f2 = make_float4(fmap(q2.x), fmap(q2.y), fmap(q2.z), fmap(q2.w));
  const float4 f3 = make_float4(fmap(q3.x), fmap(q3.y), fmap(q3.z), fmap(q3.w));
  bf16x8 qf0, qf1;
  qf0[0] = (short)c2bf(f0.x); qf0[1] = (short)c2bf(f0.y);
  qf0[2] = (short)c2bf(f0.z); qf0[3] = (short)c2bf(f0.w);
  qf0[4] = (short)c2bf(f1.x); qf0[5] = (short)c2bf(f1.y);
  qf0[6] = (short)c2bf(f1.z); qf0[7] = (short)c2bf(f1.w);
  qf1[0] = (short)c2bf(f2.x); qf1[1] = (short)c2bf(f2.y);
  qf1[2] = (short)c2bf(f2.z); qf1[3] = (short)c2bf(f2.w);
  qf1[4] = (short)c2bf(f3.x); qf1[5] = (short)c2bf(f3.y);
  qf1[6] = (short)c2bf(f3.z); qf1[7] = (short)c2bf(f3.w);
  // zden inter-chunk partial: fmap(Q[trow]) . kpre over this lane's d-slices
  float zp = f0.x * kp0.x + f0.y * kp0.y + f0.z * kp0.z + f0.w * kp0.w
           + f1.x * kp1.x + f1.y * kp1.y + f1.z * kp1.z + f1.w * kp1.w
           + f2.x * kp2.x + f2.y * kp2.y + f2.z * kp2.z + f2.w * kp2.w
           + f3.x * kp3.x + f3.y * kp3.y + f3.z * kp3.z + f3.w * kp3.w;
  __syncthreads();  // B1: Ks + Vt complete

  // ---- QK^T, swapped: lane holds attn[t = trow][s = nt*16 + lg*4 + r] ----
  f32x4 aT[4];
#pragma unroll
  for (int nt = 0; nt < 4; ++nt) {
    const int srow = nt * 16 + lane15;
    f32x4 a = {0.f, 0.f, 0.f, 0.f};
    a = MFMA(*(const bf16x8*)&Ks[sidx(srow, lg * 8)], qf0, a);
    a = MFMA(*(const bf16x8*)&Ks[sidx(srow, (lg + 4) * 8)], qf1, a);
    aT[nt] = a;
  }
  __syncthreads();  // B2: all waves' Ks reads done (Ks becomes the attn buffer)

  // ---- mask + rowsum + attn rows into Ks (wave-local rows) ----
  float rs = 0.f;
#pragma unroll
  for (int nt = 0; nt < 4; ++nt) {
    us4 w;
#pragma unroll
    for (int r = 0; r < 4; ++r) {
      const int sc = nt * 16 + lg * 4 + r;
      const float v = (sc <= trow) ? aT[nt][r] : 0.f;
      rs += v;
      w[r] = c2bf(v);
    }
    *(us4*)&Ks[sidx(trow, nt * 16 + lg * 4)] = w;
  }
  // denominator for row trow: reduce the 4 lg-partials; zv stays lane-local
  float den = rs + zp;
  den += __shfl_xor(den, 16);
  den += __shfl_xor(den, 32);
  const float zv = 1.f / (den + EPSF);

  // ---- out^T-frags: lane holds out[trow][e = nt*16 + lg*4 + r] -> float4 stores ----
  const bf16x8 af0 = *(const bf16x8*)&Ks[sidx(trow, lg * 8)];
  const bf16x8 af1 = *(const bf16x8*)&Ks[sidx(trow, 32 + lg * 8)];
  const size_t obase = ((size_t)(n * L_ + l0 + trow)) * ROWF + h * 64;
#pragma unroll
  for (int nt = 0; nt < 4; ++nt) {
    const int brow = nt * 16 + lane15;   // Vt row (e) window
    f32x4 o = {0.f, 0.f, 0.f, 0.f};
    o = MFMA(*(const bf16x8*)&Vt[sidx(brow, lg * 8)], af0, o);
    o = MFMA(*(const bf16x8*)&Vt[sidx(brow, (lg + 4) * 8)], af1, o);
    o = MFMA(stf0[nt], qf0, o);
    o = MFMA(stf1[nt], qf1, o);
    const float4 w = make_float4(o[0] * zv, o[1] * zv, o[2] * zv, o[3] * zv);
    *(float4*)&out[obase + nt * 16 + lg * 4] = w;
  }
}

extern "C" void kernel_launch(void* const* d_in, const int* in_sizes, int n_in,
                              void* d_out, int out_size, void* d_ws, size_t ws_size,
                              hipStream_t stream) {
  const float* queries = (const float*)d_in[0];
  const float* keys    = (const float*)d_in[1];
  const float* values  = (const float*)d_in[2];
  float* out = (float*)d_out;

  // workspace layout:
  //  Tws [NH_*NC_][4096] bf16  (chunk totals -> in-place exclusive prefixes; plain e*64+d)
  //  Kcs [NH_*NC_][64]   fp32  (chunk colsums -> exclusive prefixes)
  const size_t t_elems = (size_t)NH_ * NC_ * 4096;
  const size_t k_elems = (size_t)NH_ * NC_ * 64;
  if (ws_size < t_elems * 2 + k_elems * 4) return;
  unsigned short* Tws = (unsigned short*)d_ws;
  float* Kcs = (float*)(Tws + t_elems);

  hipLaunchKernelGGL(k_chunk_tot, dim3(NH_ * NC_), dim3(256), 0, stream, keys, values, Tws, Kcs);
  hipLaunchKernelGGL(k_scan, dim3(512 + 8), dim3(256), 0, stream, Tws, Kcs);
  hipLaunchKernelGGL(k_output, dim3(NH_ * NC_), dim3(256), 0, stream,
                     queries, keys, values, Tws, Kcs, out);
}

// Round 12
// 91.805 us; speedup vs baseline: 1.0766x; 1.0766x over previous
//
#include <hip/hip_runtime.h>
#include <hip/hip_bf16.h>
#include <math.h>

// Problem constants: [N, L, H, D] = [4, 8192, 8, 64], Dv = 64, fp32 in/out.
#define N_    4
#define L_    8192
#define H_    8
#define NH_   32           // N*H
#define CHK   64           // chunk length
#define NC_   128          // chunks per (n,h)
#define ROWF  512          // H_*D_ floats between consecutive l
#define EPSF  1e-6f

typedef __attribute__((ext_vector_type(8))) short bf16x8;   // 8 bf16 = 4 VGPRs
typedef __attribute__((ext_vector_type(4))) float f32x4;
typedef __attribute__((ext_vector_type(4))) unsigned short us4;

__device__ __forceinline__ float fmap(float x) { return x > 0.f ? x + 1.f : __expf(x); }

// native conversion: compiler fuses adjacent pairs into v_cvt_pk_bf16_f32
__device__ __forceinline__ unsigned short c2bf(float x) {
  __hip_bfloat16 b = __float2bfloat16(x);
  return *reinterpret_cast<unsigned short*>(&b);
}
__device__ __forceinline__ float bf2f(unsigned short u) {
  return __uint_as_float(((unsigned)u) << 16);
}

// Swizzled ushort index into a row-major [64] bf16 tile (row stride 128 B).
// Tws is stored in this same swizzled image -> C stages it with linear copies.
__device__ __forceinline__ int sidx(int row, int col) {
  return row * 64 + (col ^ ((row & 7) << 3));
}

__device__ __forceinline__ f32x4 MFMA(bf16x8 a, bf16x8 b, f32x4 c) {
  return __builtin_amdgcn_mfma_f32_16x16x32_bf16(a, b, c, 0, 0, 0);
}

// ---------------- Pass A: per-chunk totals T_c (direct frag stores, swizzled image) ----------------
__global__ __launch_bounds__(256) void k_chunk_tot(const float* __restrict__ keys,
                                                   const float* __restrict__ values,
                                                   unsigned short* __restrict__ Tws,
                                                   float* __restrict__ Kcs) {
  __shared__ __align__(16) unsigned short Kt[64 * 64];  // K^T [d][s] (fmap, bf16)
  __shared__ __align__(16) unsigned short Vt[64 * 64];  // V^T [e][s]
  __shared__ float kacc[64];
  const int bid = blockIdx.x;             // nh*NC_ + c
  const int nh = bid / NC_, c = bid % NC_;
  const int n = nh / H_, h = nh % H_;
  const int tid = threadIdx.x;
  const int lane = tid & 63;
  const int wv = tid >> 6;
  const int lane15 = lane & 15, lg = lane >> 4;
  const int arow = wv * 16 + lane15;      // e-row for the V fragment

  if (tid < 64) kacc[tid] = 0.f;

  // transposed staging: thread owns column d, 16 rows (coalesced across lanes)
  const int d = tid & 63, sg = tid >> 6;
  const size_t gbase = ((size_t)(n * L_ + c * CHK)) * ROWF + h * 64 + d;
  float kr[16], vr[16];
#pragma unroll
  for (int i = 0; i < 16; ++i) kr[i] = keys[gbase + (size_t)(sg * 16 + i) * ROWF];
#pragma unroll
  for (int i = 0; i < 16; ++i) vr[i] = values[gbase + (size_t)(sg * 16 + i) * ROWF];

  float kpart = 0.f;
#pragma unroll
  for (int i = 0; i < 16; ++i) { kr[i] = fmap(kr[i]); kpart += kr[i]; }
#pragma unroll
  for (int i = 0; i < 16; i += 4) {
    us4 wk, wvv;
#pragma unroll
    for (int j = 0; j < 4; ++j) { wk[j] = c2bf(kr[i + j]); wvv[j] = c2bf(vr[i + j]); }
    *(us4*)&Kt[sidx(d, sg * 16 + i)] = wk;
    *(us4*)&Vt[sidx(d, sg * 16 + i)] = wvv;
  }
  atomicAdd(&kacc[d], kpart);   // LDS atomics drain before the barrier
  __syncthreads();              // B1: tiles + kacc complete

  // swapped MFMA: lane holds T[e = arow][d = nt*16 + lg*4 + r]
  const bf16x8 av0 = *(const bf16x8*)&Vt[sidx(arow, lg * 8)];
  const bf16x8 av1 = *(const bf16x8*)&Vt[sidx(arow, (lg + 4) * 8)];
  unsigned short* Tp = Tws + (size_t)bid * 4096;
#pragma unroll
  for (int nt = 0; nt < 4; ++nt) {
    const int brow = nt * 16 + lane15;   // d-window
    f32x4 acc = {0.f, 0.f, 0.f, 0.f};
    acc = MFMA(*(const bf16x8*)&Kt[sidx(brow, lg * 8)], av0, acc);
    acc = MFMA(*(const bf16x8*)&Kt[sidx(brow, (lg + 4) * 8)], av1, acc);
    us4 w;
#pragma unroll
    for (int r = 0; r < 4; ++r) w[r] = c2bf(acc[r]);
    // direct store in the swizzled image (C stages with linear uint4 copies)
    *(us4*)&Tp[sidx(arow, nt * 16 + lg * 4)] = w;
  }
  if (tid < 64) Kcs[(size_t)bid * 64 + tid] = kacc[tid];
}

// ---------------- Pass B: in-place exclusive prefix over chunks (depth 32, 4-wide) ----------------
// Elementwise at fixed flat index -> layout/swizzle agnostic.
__global__ __launch_bounds__(256) void k_scan(unsigned short* __restrict__ Tws,
                                              float* __restrict__ Kcs) {
  const int tid = threadIdx.x;
  if (blockIdx.x < 512) {
    const int gid = blockIdx.x * 256 + tid;          // 0 .. 131071
    const int nh = gid >> 12, de = gid & 4095;
    unsigned short* p = Tws + (size_t)nh * NC_ * 4096 + de;
    float run = 0.f;
    for (int s = 0; s < 32; ++s) {
      const float x0 = bf2f(p[(size_t)(s * 4 + 0) * 4096]);
      const float x1 = bf2f(p[(size_t)(s * 4 + 1) * 4096]);
      const float x2 = bf2f(p[(size_t)(s * 4 + 2) * 4096]);
      const float x3 = bf2f(p[(size_t)(s * 4 + 3) * 4096]);
      p[(size_t)(s * 4 + 0) * 4096] = c2bf(run);
      p[(size_t)(s * 4 + 1) * 4096] = c2bf(run + x0);
      p[(size_t)(s * 4 + 2) * 4096] = c2bf(run + x0 + x1);
      p[(size_t)(s * 4 + 3) * 4096] = c2bf(run + x0 + x1 + x2);
      run += x0 + x1 + x2 + x3;
    }
  } else {
    const int gid = (blockIdx.x - 512) * 256 + tid;  // 0 .. 2047
    const int nh = gid >> 6, d = gid & 63;
    float* p = Kcs + (size_t)nh * NC_ * 64 + d;
    float run = 0.f;
    for (int s = 0; s < 32; ++s) {
      const float x0 = p[(size_t)(s * 4 + 0) * 64];
      const float x1 = p[(size_t)(s * 4 + 1) * 64];
      const float x2 = p[(size_t)(s * 4 + 2) * 64];
      const float x3 = p[(size_t)(s * 4 + 3) * 64];
      p[(size_t)(s * 4 + 0) * 64] = run;
      p[(size_t)(s * 4 + 1) * 64] = run + x0;
      p[(size_t)(s * 4 + 2) * 64] = run + x0 + x1;
      p[(size_t)(s * 4 + 3) * 64] = run + x0 + x1 + x2;
      run += x0 + x1 + x2 + x3;
    }
  }
}

// ---------------- Pass C: per-chunk output; prefetch-all + LDS-staged St ----------------
__global__ __launch_bounds__(256, 4) void k_output(const float* __restrict__ queries,
                                                   const float* __restrict__ keys,
                                                   const float* __restrict__ values,
                                                   const unsigned short* __restrict__ Pws,
                                                   const float* __restrict__ Kpre,
                                                   float* __restrict__ out) {
  __shared__ __align__(16) unsigned short Ks[64 * 64];  // K rows (fmap); after B2: attn rows
  __shared__ __align__(16) unsigned short Vt[64 * 64];  // V^T [e][s]
  __shared__ __align__(16) unsigned short St[64 * 64];  // S^T prefix (swizzled image)

  // XCD-aware swizzle: 4096 % 8 == 0 -> bijective
  const int wg = blockIdx.x;
  const int bid = (wg & 7) * (NH_ * NC_ / 8) + (wg >> 3);
  const int nh = bid / NC_, c = bid % NC_;
  const int n = nh / H_, h = nh % H_;
  const int tid = threadIdx.x;
  const int lane = tid & 63;
  const int wv = tid >> 6;
  const int lane15 = lane & 15, lg = lane >> 4;
  const int t0w = wv * 16;
  const int trow = t0w + lane15;          // this lane's attn/output row (wave-local)
  const int l0 = c * CHK;
  const size_t tb = (size_t)bid * 4096;
  const size_t kb = (size_t)bid * 64;

  // ---- prefetch phase: issue ALL global loads ----
  // Q (row trow)
  const size_t qg = ((size_t)(n * L_ + l0 + trow)) * ROWF + h * 64;
  const float4 q0 = *(const float4*)&queries[qg + lg * 8];
  const float4 q1 = *(const float4*)&queries[qg + lg * 8 + 4];
  const float4 q2 = *(const float4*)&queries[qg + 32 + lg * 8];
  const float4 q3 = *(const float4*)&queries[qg + 32 + lg * 8 + 4];
  // K rows (coalesced float4)
  const int r0 = tid >> 4, c4 = (tid & 15) * 4;
  float4 krow[4];
#pragma unroll
  for (int rep = 0; rep < 4; ++rep)
    krow[rep] = *(const float4*)&keys[((size_t)(n * L_ + l0 + r0 + rep * 16)) * ROWF + h * 64 + c4];
  // V^T (transposed scalar, coalesced across lanes)
  const int d = tid & 63, sg = tid >> 6;
  const size_t vbase = ((size_t)(n * L_ + l0)) * ROWF + h * 64 + d;
  float vr[16];
#pragma unroll
  for (int i = 0; i < 16; ++i) vr[i] = values[vbase + (size_t)(sg * 16 + i) * ROWF];
  // St: 2 linear uint4 copies (swizzled image; coalesced, L3-hot)
  const uint4 st0 = *(const uint4*)&Pws[tb + tid * 8];
  const uint4 st1 = *(const uint4*)&Pws[tb + (tid + 256) * 8];
  // kpre slices for the zden dot (broadcast within 16-lane groups; L2-hot)
  const float4 kp0 = *(const float4*)&Kpre[kb + lg * 8];
  const float4 kp1 = *(const float4*)&Kpre[kb + lg * 8 + 4];
  const float4 kp2 = *(const float4*)&Kpre[kb + 32 + lg * 8];
  const float4 kp3 = *(const float4*)&Kpre[kb + 32 + lg * 8 + 4];

  // ---- convert + LDS writes ----
#pragma unroll
  for (int rep = 0; rep < 4; ++rep) {
    us4 uk;
    uk[0] = c2bf(fmap(krow[rep].x)); uk[1] = c2bf(fmap(krow[rep].y));
    uk[2] = c2bf(fmap(krow[rep].z)); uk[3] = c2bf(fmap(krow[rep].w));
    *(us4*)&Ks[sidx(r0 + rep * 16, c4)] = uk;
  }
#pragma unroll
  for (int i = 0; i < 16; i += 4) {
    us4 w;
#pragma unroll
    for (int j = 0; j < 4; ++j) w[j] = c2bf(vr[i + j]);
    *(us4*)&Vt[sidx(d, sg * 16 + i)] = w;
  }
  *(uint4*)&St[tid * 8] = st0;
  *(uint4*)&St[(tid + 256) * 8] = st1;
  // Q: fmap in fp32 (also feeds the zden dot), then convert
  const float4 f0 = make_float4(fmap(q0.x), fmap(q0.y), fmap(q0.z), fmap(q0.w));
  const float4 f1 = make_float4(fmap(q1.x), fmap(q1.y), fmap(q1.z), fmap(q1.w));
  const float4 f2 = make_float4(fmap(q2.x), fmap(q2.y), fmap(q2.z), fmap(q2.w));
  const float4 f3 = make_float4(fmap(q3.x), fmap(q3.y), fmap(q3.z), fmap(q3.w));
  bf16x8 qf0, qf1;
  qf0[0] = (short)c2bf(f0.x); qf0[1] = (short)c2bf(f0.y);
  qf0[2] = (short)c2bf(f0.z); qf0[3] = (short)c2bf(f0.w);
  qf0[4] = (short)c2bf(f1.x); qf0[5] = (short)c2bf(f1.y);
  qf0[6] = (short)c2bf(f1.z); qf0[7] = (short)c2bf(f1.w);
  qf1[0] = (short)c2bf(f2.x); qf1[1] = (short)c2bf(f2.y);
  qf1[2] = (short)c2bf(f2.z); qf1[3] = (short)c2bf(f2.w);
  qf1[4] = (short)c2bf(f3.x); qf1[5] = (short)c2bf(f3.y);
  qf1[6] = (short)c2bf(f3.z); qf1[7] = (short)c2bf(f3.w);
  // zden inter-chunk partial: fmap(Q[trow]) . kpre over this lane's d-slices
  float zp = f0.x * kp0.x + f0.y * kp0.y + f0.z * kp0.z + f0.w * kp0.w
           + f1.x * kp1.x + f1.y * kp1.y + f1.z * kp1.z + f1.w * kp1.w
           + f2.x * kp2.x + f2.y * kp2.y + f2.z * kp2.z + f2.w * kp2.w
           + f3.x * kp3.x + f3.y * kp3.y + f3.z * kp3.z + f3.w * kp3.w;
  __syncthreads();  // B1: Ks + Vt + St complete

  // ---- QK^T, swapped: lane holds attn[t = trow][s = nt*16 + lg*4 + r] ----
  f32x4 aT[4];
#pragma unroll
  for (int nt = 0; nt < 4; ++nt) {
    const int srow = nt * 16 + lane15;
    f32x4 a = {0.f, 0.f, 0.f, 0.f};
    a = MFMA(*(const bf16x8*)&Ks[sidx(srow, lg * 8)], qf0, a);
    a = MFMA(*(const bf16x8*)&Ks[sidx(srow, (lg + 4) * 8)], qf1, a);
    aT[nt] = a;
  }
  __syncthreads();  // B2: all waves' Ks reads done (Ks becomes the attn buffer)

  // ---- mask + rowsum + attn rows into Ks (wave-local rows) ----
  float rs = 0.f;
#pragma unroll
  for (int nt = 0; nt < 4; ++nt) {
    us4 w;
#pragma unroll
    for (int r = 0; r < 4; ++r) {
      const int sc = nt * 16 + lg * 4 + r;
      const float v = (sc <= trow) ? aT[nt][r] : 0.f;
      rs += v;
      w[r] = c2bf(v);
    }
    *(us4*)&Ks[sidx(trow, nt * 16 + lg * 4)] = w;
  }
  // denominator for row trow: reduce the 4 lg-partials; zv stays lane-local
  float den = rs + zp;
  den += __shfl_xor(den, 16);
  den += __shfl_xor(den, 32);
  const float zv = 1.f / (den + EPSF);

  // ---- out^T-frags: lane holds out[trow][e = nt*16 + lg*4 + r] -> float4 stores ----
  const bf16x8 af0 = *(const bf16x8*)&Ks[sidx(trow, lg * 8)];
  const bf16x8 af1 = *(const bf16x8*)&Ks[sidx(trow, 32 + lg * 8)];
  const size_t obase = ((size_t)(n * L_ + l0 + trow)) * ROWF + h * 64;
#pragma unroll
  for (int nt = 0; nt < 4; ++nt) {
    const int brow = nt * 16 + lane15;   // Vt/St row (e) window
    f32x4 o = {0.f, 0.f, 0.f, 0.f};
    o = MFMA(*(const bf16x8*)&Vt[sidx(brow, lg * 8)], af0, o);
    o = MFMA(*(const bf16x8*)&Vt[sidx(brow, (lg + 4) * 8)], af1, o);
    o = MFMA(*(const bf16x8*)&St[sidx(brow, lg * 8)], qf0, o);
    o = MFMA(*(const bf16x8*)&St[sidx(brow, (lg + 4) * 8)], qf1, o);
    const float4 w = make_float4(o[0] * zv, o[1] * zv, o[2] * zv, o[3] * zv);
    *(float4*)&out[obase + nt * 16 + lg * 4] = w;
  }
}

extern "C" void kernel_launch(void* const* d_in, const int* in_sizes, int n_in,
                              void* d_out, int out_size, void* d_ws, size_t ws_size,
                              hipStream_t stream) {
  const float* queries = (const float*)d_in[0];
  const float* keys    = (const float*)d_in[1];
  const float* values  = (const float*)d_in[2];
  float* out = (float*)d_out;

  // workspace layout:
  //  Tws [NH_*NC_][4096] bf16  (chunk totals -> in-place exclusive prefixes; swizzled image)
  //  Kcs [NH_*NC_][64]   fp32  (chunk colsums -> exclusive prefixes)
  const size_t t_elems = (size_t)NH_ * NC_ * 4096;
  const size_t k_elems = (size_t)NH_ * NC_ * 64;
  if (ws_size < t_elems * 2 + k_elems * 4) return;
  unsigned short* Tws = (unsigned short*)d_ws;
  float* Kcs = (float*)(Tws + t_elems);

  hipLaunchKernelGGL(k_chunk_tot, dim3(NH_ * NC_), dim3(256), 0, stream, keys, values, Tws, Kcs);
  hipLaunchKernelGGL(k_scan, dim3(512 + 8), dim3(256), 0, stream, Tws, Kcs);
  hipLaunchKernelGGL(k_output, dim3(NH_ * NC_), dim3(256), 0, stream,
                     queries, keys, values, Tws, Kcs, out);
}